// Round 5
// baseline (374.355 us; speedup 1.0000x reference)
//
#include <hip/hip_runtime.h>
#include <math.h>

typedef unsigned short u16;
typedef __attribute__((ext_vector_type(8))) short bf16x8;
typedef __attribute__((ext_vector_type(4))) float f32x4;
typedef __attribute__((ext_vector_type(4))) int i32x4;
typedef __attribute__((ext_vector_type(4))) short s16x4;
typedef __attribute__((ext_vector_type(4))) unsigned short u16x4;

#define MFMA16(a,b,c) __builtin_amdgcn_mfma_f32_16x16x32_bf16((a),(b),(c),0,0,0)

__device__ __forceinline__ u16 f2bf(float x){
  unsigned int u = __float_as_uint(x);
  u += 0x7fffu + ((u >> 16) & 1u);   // RNE
  return (u16)(u >> 16);
}
__device__ __forceinline__ float bf2f(u16 x){
  return __uint_as_float(((unsigned)x) << 16);
}
// async global->LDS, 16B per lane. LDS image must be lane-linear.
__device__ __forceinline__ void gload16(const void* g, void* l){
  __builtin_amdgcn_global_load_lds((const __attribute__((address_space(1))) void*)g,
                                   (__attribute__((address_space(3))) void*)l, 16, 0, 0);
}

// ---------------------------------------------------------------------------
// prep: fp32->bf16 + weight transposes + maskP packing.
// qlb[8192][1024] = [q1 | last]  (concat along K so Q-proj is one K=1024 GEMM)
// WtQ2[512][1024] = [Wqf | Wql]  (B^T layout, concat along K)
// maskP[b][rt(16)][col(1024)][p(16)] bf16, p = row-in-16 (MFMA C-layout order).
// grid = 4096 x 256.
// ---------------------------------------------------------------------------
__global__ __launch_bounds__(256) void prep(
    const float* __restrict__ nodes, const float* __restrict__ q1, const float* __restrict__ lastn,
    const float* __restrict__ mask,
    const float* __restrict__ Wqf, const float* __restrict__ Wql, const float* __restrict__ Wk,
    const float* __restrict__ Wv, const float* __restrict__ Wc,
    u16* __restrict__ nodesb, u16* __restrict__ qlb,
    u16* __restrict__ WtKV, u16* __restrict__ WtQ2, u16* __restrict__ WtC,
    u16* __restrict__ maskP)
{
  const int tid = blockIdx.x * 256 + threadIdx.x;
  const int NT = 1048576;
  for (int i = tid; i < 4194304; i += NT) {
    float4 v = ((const float4*)nodes)[i];
    u16x4 o; o[0]=f2bf(v.x); o[1]=f2bf(v.y); o[2]=f2bf(v.z); o[3]=f2bf(v.w);
    *(u16x4*)&nodesb[i*4] = o;
  }
  {
    const int m = tid >> 7, k4 = (tid & 127)*4;
    float4 v = ((const float4*)q1)[tid];
    u16x4 o; o[0]=f2bf(v.x); o[1]=f2bf(v.y); o[2]=f2bf(v.z); o[3]=f2bf(v.w);
    *(u16x4*)&qlb[m*1024 + k4] = o;
    v = ((const float4*)lastn)[tid];
    o[0]=f2bf(v.x); o[1]=f2bf(v.y); o[2]=f2bf(v.z); o[3]=f2bf(v.w);
    *(u16x4*)&qlb[m*1024 + 512 + k4] = o;
  }
  if (tid < 262144) {
    int n = tid >> 9, k = tid & 511;
    WtQ2[n*1024 + k]       = f2bf(Wqf[k*512 + n]);
    WtQ2[n*1024 + 512 + k] = f2bf(Wql[k*512 + n]);
    WtC[tid]  = f2bf(Wc[k*512 + n]);
  }
  if (tid < 524288) {
    int n = tid >> 9, k = tid & 511;
    WtKV[tid] = f2bf(n < 512 ? Wk[k*512 + n] : Wv[k*512 + (n-512)]);
  }
  if (tid < 524288) {  // maskP: tid = (b*16 + rt)*1024 + c
    int brt = tid >> 10, c = tid & 1023;
    const float* mp = mask + (brt*16)*1024 + c;
    u16 vals[16];
    #pragma unroll
    for (int p=0;p<16;p++) vals[p] = f2bf(mp[p*1024]);
    *(i32x4*)&maskP[tid*16]     = *(i32x4*)&vals[0];
    *(i32x4*)&maskP[tid*16 + 8] = *(i32x4*)&vals[8];
  }
}

// ---------------------------------------------------------------------------
// kvq: ONE code path, 8 waves (512 thr), 128(M)x256(N) tile, BK=32 dbuf.
// (R3 version, measured 93.5us — R4's counted-vmcnt 3-deep pipeline was
// neutral-to-worse: T4 pays only inside an 8-phase interleave, not grafted
// onto a 1-phase loop.)
//   bids 0..127    : Q tiles  (A=qlb [8192][1024], B=WtQ2 [512][1024], 32 kc)
//   bids 128..1151 : KV tiles (A=nodesb [32768][512], B=WtKV [1024][512], 16 kc)
// ---------------------------------------------------------------------------
__global__ __launch_bounds__(512, 2) void kvq(
    const u16* __restrict__ Akv, const u16* __restrict__ Bkv,
    const u16* __restrict__ Aq,  const u16* __restrict__ Bq,
    u16* __restrict__ Kout, u16* __restrict__ Vout, u16* __restrict__ Qout)
{
  __shared__ u16 smem[24576];   // 49152 B: 2 x (A 8KB + B 16KB)
  const int t = threadIdx.x, w = t >> 6, l = t & 63, q = l >> 4, ln = l & 15;
  const int wr = w >> 2, wc = w & 3;
  const int wm = wr * 64, wn = wc * 64;

  const bool isq = blockIdx.x < 128;
  int mb, nb, ksteps, kstr;
  const u16 *Ab, *Bb;
  if (isq) {
    const int bid = blockIdx.x;
    mb = bid >> 1; nb = bid & 1;
    ksteps = 32; kstr = 1024; Ab = Aq; Bb = Bq;
  } else {
    const int bid = blockIdx.x - 128;
    mb = (bid >> 5)*8 + (bid & 7);        // XCD swizzle (same-A blocks share XCD)
    nb = (bid >> 3) & 3;
    ksteps = 16; kstr = 512; Ab = Akv; Bb = Bkv;
  }
  const int m0 = mb*128, n0 = nb*256;

  f32x4 acc[4][4];
  #pragma unroll
  for (int i=0;i<4;i++)
    #pragma unroll
    for (int j=0;j<4;j++)
      #pragma unroll
      for (int r=0;r<4;r++) acc[i][j][r] = 0.f;

  // staging: A 8KB = 512 lanes x 16B; B 16KB = 512 lanes x 2 x 16B
  const u16* Aaddr = Ab + (m0 + (t & 127))*kstr + (t >> 7)*8;
  const u16* Baddr = Bb + (n0 + (t & 255))*kstr + (t >> 8)*8;

  #define STAGE(kc_, b_) { \
    u16* s = smem + (b_)*12288; \
    gload16(Aaddr + (kc_)*32,      &s[t*8]); \
    gload16(Baddr + (kc_)*32,      &s[4096 + t*8]); \
    gload16(Baddr + 16 + (kc_)*32, &s[4096 + (t+512)*8]); }

  STAGE(0, 0);
  for (int kc = 0; kc < ksteps; kc++) {
    __syncthreads();
    if (kc + 1 < ksteps) STAGE(kc+1, (kc+1)&1);
    const u16* sa = smem + (kc&1)*12288;
    const u16* sb = sa + 4096;
    bf16x8 af[4], bfr[4];
    #pragma unroll
    for (int i=0;i<4;i++) af[i]  = *(bf16x8*)&sa[(q*128 + wm + i*16 + ln)*8];
    #pragma unroll
    for (int j=0;j<4;j++) bfr[j] = *(bf16x8*)&sb[(q*256 + wn + j*16 + ln)*8];
    #pragma unroll
    for (int i=0;i<4;i++)
      #pragma unroll
      for (int j=0;j<4;j++)
        acc[i][j] = MFMA16(af[i], bfr[j], acc[i][j]);
  }
  #undef STAGE

  // ---- epilogue: four 64-col passes via 64x140 buffer (17920 B) ----
  const float scale = isq ? 0.17677669529663687f : 1.0f;
  const int bb_ = mb >> 3, mloc = (mb & 7)*128;   // kv decode
  const int bbq = mb >> 1, pm0 = (mb & 1)*128;    // q  decode
  for (int h = 0; h < 4; ++h) {
    __syncthreads();
    if (wc == h) {
      #pragma unroll
      for (int i=0;i<4;i++)
        #pragma unroll
        for (int j=0;j<4;j++) {
          s16x4 o;
          #pragma unroll
          for (int r=0;r<4;r++) o[r] = (short)f2bf(acc[i][j][r]*scale);
          *(s16x4*)&smem[(j*16 + ln)*140 + wm + i*16 + q*4] = o;
        }
    }
    __syncthreads();
    #pragma unroll
    for (int hc=0; hc<2; ++hc) {
      if (isq) {
        const int head = nb*8 + h*2 + hc;
        const int m_ = t >> 2, d0 = (t & 3)*8;
        u16 v[8];
        #pragma unroll
        for (int dd=0;dd<8;dd++) v[dd] = smem[(hc*32 + d0 + dd)*140 + m_];
        *(i32x4*)&Qout[((bbq*16 + head)*256 + pm0 + m_)*32 + d0] = *(i32x4*)&v[0];
      } else if (nb < 2) {
        const int head = nb*8 + h*2 + hc;
        const int m_ = t >> 2, d0 = (t & 3)*8;
        u16 v[8];
        #pragma unroll
        for (int dd=0;dd<8;dd++) v[dd] = smem[(hc*32 + d0 + dd)*140 + m_];
        *(i32x4*)&Kout[((bb_*16 + head)*1024 + mloc + m_)*32 + d0] = *(i32x4*)&v[0];
      } else {
        const int vh = (nb-2)*8 + h*2 + hc;
        const int d = t >> 4, mo = (t & 15)*8;
        *(i32x4*)&Vout[((bb_*16 + vh)*32 + d)*1024 + mloc + mo]
            = *(i32x4*)&smem[(hc*32 + d)*140 + mo];
      }
    }
  }
}

// ---------------------------------------------------------------------------
// attn v2: ONE block per (b,h), all 256 pomo rows. grid = 512, 4 waves,
// wave w owns rows w*64..w*64+63 (4 row-groups of 16).
// vs v1 (2048 blocks x 64 rows): K/V/Q staged ONCE per (b,h) instead of 4x,
// barrier count /4, and per 16KB staged chunk each wave now runs 64 MFMAs +
// 128 exps (4x density). Mask loads software-pipelined across row-groups
// (two named register sets, fully unrolled -> static indexing).
// XCD chunk-swizzle: bid%8 = XCD, so each XCD owns 4 complete batches
// (mask slices + K/V/Q stay in its L2).
// LDS 37.9KB; grid 2 blocks/CU -> VGPR unconstrained.
// ---------------------------------------------------------------------------
__global__ __launch_bounds__(256) void attn(const u16* __restrict__ Qg, const u16* __restrict__ Kg,
                                            const u16* __restrict__ Vtg, const u16* __restrict__ maskP,
                                            u16* __restrict__ Og)
{
  const int bid = blockIdx.x;                  // 0..511
  const int bh = (bid & 7)*64 + (bid >> 3);    // 64 consecutive bh per XCD
  const int h = bh & 15, bb = bh >> 4;
  const int t = threadIdx.x, w = t >> 6, l = t & 63, q = l >> 4, ln = l & 15;
  __shared__ u16 Qs[8192];     // [qk(4)][row(256)][8]
  __shared__ u16 Ks[4096];     // [qk(4)][m(128)][8]
  __shared__ u16 Vs[4096];     // [kg(16)][d(32)][8]
  __shared__ u16 Ps[2560];     // per wave [16][40]
  u16* Pw = &Ps[w*640];
  const int qbase = (bb*16 + h)*256*32;
  #pragma unroll
  for (int c=0;c<4;c++)
    gload16(&Qg[qbase + t*32 + c*8], &Qs[(c*256 + t)*8]);
  const int kbase = (bb*16 + h)*1024*32;
  const int vbase = (bb*16 + h)*32*1024;
  float rs[4][4];
  f32x4 oacc[4][2];
  #pragma unroll
  for (int rg=0;rg<4;rg++) {
    #pragma unroll
    for (int r=0;r<4;r++) rs[rg][r] = 0.f;
    #pragma unroll
    for (int dt=0;dt<2;dt++)
      #pragma unroll
      for (int r=0;r<4;r++) oacc[rg][dt][r] = 0.f;
  }
  __syncthreads();               // Q resident (barrier drains vmcnt)
  bf16x8 aq[4];
  #pragma unroll
  for (int rg=0;rg<4;rg++) aq[rg] = *(bf16x8*)&Qs[(q*256 + w*64 + rg*16 + ln)*8];
  const u16* mbase = maskP + (bb*16 + w*4)*16384 + q*4;   // + rg*16384
  u16x4 mqA[8], mqB[8];

  #define RG_BODY(rg, MQC, MQN) { \
    if ((rg) < 3) { \
      _Pragma("unroll") \
      for (int j2=0;j2<8;j2++) \
        MQN[j2] = *(const u16x4*)&mbase[((rg)+1)*16384 + (mc*128 + j2*16 + ln)*16]; \
    } \
    _Pragma("unroll") \
    for (int ch=0; ch<4; ch++) { \
      bf16x8 bk0 = *(bf16x8*)&Ks[(q*128 + (ch*2+0)*16 + ln)*8]; \
      bf16x8 bk1 = *(bf16x8*)&Ks[(q*128 + (ch*2+1)*16 + ln)*8]; \
      f32x4 zz = {0.f,0.f,0.f,0.f}; \
      f32x4 s0 = MFMA16(aq[rg], bk0, zz); \
      f32x4 s1 = MFMA16(aq[rg], bk1, zz); \
      _Pragma("unroll") \
      for (int r=0;r<4;r++) { \
        float e0 = __expf(s0[r] + bf2f(MQC[ch*2+0][r])); \
        float e1 = __expf(s1[r] + bf2f(MQC[ch*2+1][r])); \
        rs[rg][r] += e0 + e1; \
        Pw[(q*4+r)*40 + ln]      = f2bf(e0); \
        Pw[(q*4+r)*40 + 16 + ln] = f2bf(e1); \
      } \
      bf16x8 ap  = *(bf16x8*)&Pw[ln*40 + q*8]; \
      bf16x8 bv0 = *(bf16x8*)&Vs[((ch*4+q)*32 + ln)*8]; \
      bf16x8 bv1 = *(bf16x8*)&Vs[((ch*4+q)*32 + 16 + ln)*8]; \
      oacc[rg][0] = MFMA16(ap, bv0, oacc[rg][0]); \
      oacc[rg][1] = MFMA16(ap, bv1, oacc[rg][1]); \
    } }

  for (int mc = 0; mc < 8; mc++) {
    __syncthreads();
    gload16(&Kg[kbase + (mc*128 + (t & 127))*32 + (t >> 7)*8],       &Ks[t*8]);
    gload16(&Kg[kbase + (mc*128 + (t & 127))*32 + ((t >> 7)+2)*8],   &Ks[(t+256)*8]);
    gload16(&Vtg[vbase + (t & 31)*1024 + mc*128 + (t >> 5)*8],       &Vs[t*8]);
    gload16(&Vtg[vbase + (t & 31)*1024 + mc*128 + ((t >> 5)+8)*8],   &Vs[(t+256)*8]);
    #pragma unroll
    for (int j2=0;j2<8;j2++)
      mqA[j2] = *(const u16x4*)&mbase[(mc*128 + j2*16 + ln)*16];
    __syncthreads();
    RG_BODY(0, mqA, mqB)
    RG_BODY(1, mqB, mqA)
    RG_BODY(2, mqA, mqB)
    RG_BODY(3, mqB, mqA)
  }
  #undef RG_BODY

  #pragma unroll
  for (int rg=0;rg<4;rg++) {
    #pragma unroll
    for (int r=0;r<4;r++) {
      float v = rs[rg][r];
      v += __shfl_xor(v,1); v += __shfl_xor(v,2); v += __shfl_xor(v,4); v += __shfl_xor(v,8);
      rs[rg][r] = __builtin_amdgcn_rcpf(v);
    }
    const int orow = bb*256 + w*64 + rg*16 + q*4;
    #pragma unroll
    for (int dt=0;dt<2;dt++)
      #pragma unroll
      for (int r=0;r<4;r++)
        Og[(orow + r)*512 + h*32 + dt*16 + ln] = f2bf(oacc[rg][dt][r]*rs[rg][r]);
  }
}

// ---------------------------------------------------------------------------
// cmbfin: fused combine-GEMM + pointer-GEMM + tanh-softmax.
// 1024 threads (16 waves), 32 rows x 1024 cols per block, grid = 256
// (1 block/CU). XCD swizzle: bid = rg*32 + bb -> all 8 row-groups of batch b
// on one XCD (nodesb[b] = 1 MB stays in that XCD's L2; 4 b's = 4 MB = L2).
// ---------------------------------------------------------------------------
__global__ __launch_bounds__(1024) void cmbfin(const u16* __restrict__ oc, const u16* __restrict__ WtC,
                                               const float* __restrict__ bias,
                                               const u16* __restrict__ nodesb, const u16* __restrict__ maskP,
                                               float* __restrict__ out)
{
  const int bid = blockIdx.x;
  const int bb = bid & 31, rg = bid >> 5;     // rg 0..7: 32-row group
  const int t = threadIdx.x, w = t >> 6, l = t & 63, q = l >> 4, ln = l & 15;
  __shared__ u16 As[16384];     // oc tile [koct(64)][row(32)][8]
  __shared__ u16 Ms[16384];     // mh tile, same layout (k = combine out col)
  __shared__ float rsL[16][32];
  const int abase = (bb*256 + rg*32)*512;
  #pragma unroll
  for (int c=0;c<2;c++) {
    int chunk = t + 1024*c;
    gload16(&oc[abase + (chunk & 31)*512 + (chunk >> 5)*8], &As[chunk*8]);
  }
  __syncthreads();
  // ---- phase 1: combine. wave w covers cols w*32..w*32+31 ----
  f32x4 acc1[2][2];
  #pragma unroll
  for (int i=0;i<2;i++)
    #pragma unroll
    for (int ct=0;ct<2;ct++)
      #pragma unroll
      for (int r=0;r<4;r++) acc1[i][ct][r] = 0.f;
  for (int kc=0;kc<16;kc++) {
    bf16x8 af[2];
    #pragma unroll
    for (int i=0;i<2;i++) af[i] = *(bf16x8*)&As[((kc*4 + q)*32 + i*16 + ln)*8];
    #pragma unroll
    for (int ct=0;ct<2;ct++) {
      int col = w*32 + ct*16 + ln;
      bf16x8 bfr = *(const bf16x8*)&WtC[col*512 + kc*32 + q*8];
      #pragma unroll
      for (int i=0;i<2;i++) acc1[i][ct] = MFMA16(af[i], bfr, acc1[i][ct]);
    }
  }
  #pragma unroll
  for (int ct=0;ct<2;ct++) {
    int gn = w*32 + ct*16 + ln;
    float bv = bias[gn];
    #pragma unroll
    for (int i=0;i<2;i++)
      #pragma unroll
      for (int r=0;r<4;r++)
        Ms[(gn >> 3)*256 + (i*16 + q*4 + r)*8 + (gn & 7)] = f2bf(acc1[i][ct][r] + bv);
  }
  __syncthreads();
  // ---- phase 2: pointer logits + softmax. wave w covers cols w*64.. ----
  float rloc[2][4] = {{0.f,0.f,0.f,0.f},{0.f,0.f,0.f,0.f}};
  const int nbase = bb*524288;
  f32x4 acc[2][4];
  #pragma unroll
  for (int i=0;i<2;i++)
    #pragma unroll
    for (int ct=0;ct<4;ct++)
      #pragma unroll
      for (int r=0;r<4;r++) acc[i][ct][r] = 0.f;
  for (int kc=0;kc<16;kc++) {
    bf16x8 af[2];
    #pragma unroll
    for (int i=0;i<2;i++) af[i] = *(bf16x8*)&Ms[((kc*4 + q)*32 + i*16 + ln)*8];
    #pragma unroll
    for (int ct=0;ct<4;ct++) {
      int col = w*64 + ct*16 + ln;
      bf16x8 bfr = *(const bf16x8*)&nodesb[nbase + col*512 + kc*32 + q*8];
      #pragma unroll
      for (int i=0;i<2;i++) acc[i][ct] = MFMA16(af[i], bfr, acc[i][ct]);
    }
  }
  const float c2 = 0.08838834764831843f;   // 2/sqrt(512)
  const int prow_base = bb*256 + rg*32;
  #pragma unroll
  for (int i=0;i<2;i++) {
    #pragma unroll
    for (int ct=0;ct<4;ct++) {
      int col0 = w*64 + ct*16 + ln;
      u16x4 mv = *(const u16x4*)&maskP[((bb*16 + rg*2 + i)*1024 + col0)*16 + q*4];
      #pragma unroll
      for (int r=0;r<4;r++) {
        float x = acc[i][ct][r] * c2;
        x = fminf(fmaxf(x, -30.f), 30.f);
        float e2 = __expf(x);
        float lg = 10.f*(e2 - 1.f)*__builtin_amdgcn_rcpf(e2 + 1.f) + bf2f(mv[r]);
        float e = __expf(lg);
        rloc[i][r] += e;
        acc[i][ct][r] = e;
      }
    }
  }
  #pragma unroll
  for (int i=0;i<2;i++)
    #pragma unroll
    for (int r=0;r<4;r++) {
      float v = rloc[i][r];
      v += __shfl_xor(v,1); v += __shfl_xor(v,2); v += __shfl_xor(v,4); v += __shfl_xor(v,8);
      rloc[i][r] = v;
    }
  if (ln == 0) {
    #pragma unroll
    for (int i=0;i<2;i++)
      #pragma unroll
      for (int r=0;r<4;r++) rsL[w][i*16 + q*4 + r] = rloc[i][r];
  }
  __syncthreads();
  float inv[2][4];
  #pragma unroll
  for (int i=0;i<2;i++)
    #pragma unroll
    for (int r=0;r<4;r++) {
      float tot = 0.f;
      #pragma unroll
      for (int ww=0;ww<16;ww++) tot += rsL[ww][i*16 + q*4 + r];
      inv[i][r] = __builtin_amdgcn_rcpf(tot);
    }
  #pragma unroll
  for (int i=0;i<2;i++)
    #pragma unroll
    for (int ct=0;ct<4;ct++) {
      int col0 = w*64 + ct*16 + ln;
      #pragma unroll
      for (int r=0;r<4;r++)
        out[(prow_base + i*16 + q*4 + r)*1024 + col0] = acc[i][ct][r]*inv[i][r];
    }
}

extern "C" void kernel_launch(void* const* d_in, const int* in_sizes, int n_in,
                              void* d_out, int out_size, void* d_ws, size_t ws_size,
                              hipStream_t stream)
{
  (void)in_sizes; (void)n_in; (void)out_size; (void)ws_size;
  const float* nodes = (const float*)d_in[0];
  const float* q1    = (const float*)d_in[1];
  const float* lastn = (const float*)d_in[2];
  const float* mask  = (const float*)d_in[3];
  const float* Wqf   = (const float*)d_in[4];
  const float* Wql   = (const float*)d_in[5];
  const float* Wk    = (const float*)d_in[6];
  const float* Wv    = (const float*)d_in[7];
  const float* Wc    = (const float*)d_in[8];
  const float* bias  = (const float*)d_in[9];
  float* out = (float*)d_out;

  char* p = (char*)d_ws;
  u16* nodesb = (u16*)p; p += 33554432;   // [32][1024][512] bf16
  u16* qlb    = (u16*)p; p += 16777216;   // [8192][1024]  = [q1 | last]
  u16* WtKV   = (u16*)p; p += 1048576;    // [1024][512]
  u16* WtQ2   = (u16*)p; p += 1048576;    // [512][1024]   = [Wqf | Wql]
  u16* WtC    = (u16*)p; p += 524288;
  u16* Kt     = (u16*)p; p += 33554432;   // K [32][16][1024][32]
  u16* Vt     = (u16*)p; p += 33554432;   // V^T [32][16][32][1024]
  u16* Qh     = (u16*)p; p += 8388608;    // Q(scaled) [32][16][256][32]
  u16* maskP  = (u16*)p; p += 16777216;   // [32][16][1024][16] bf16
  u16* oc  = qlb;   // dead after kvq

  prep<<<4096, 256, 0, stream>>>(nodes, q1, lastn, mask, Wqf, Wql, Wk, Wv, Wc,
                                 nodesb, qlb, WtKV, WtQ2, WtC, maskP);
  kvq<<<1152, 512, 0, stream>>>(nodesb, WtKV, qlb, WtQ2, Kt, Vt, Qh);
  attn<<<512, 256, 0, stream>>>(Qh, Kt, Vt, maskP, oc);
  cmbfin<<<256, 1024, 0, stream>>>(oc, WtC, bias, nodesb, maskP, out);
}

// Round 6
// 342.149 us; speedup vs baseline: 1.0941x; 1.0941x over previous
//
#include <hip/hip_runtime.h>
#include <math.h>

typedef unsigned short u16;
typedef __attribute__((ext_vector_type(8))) short bf16x8;
typedef __attribute__((ext_vector_type(4))) float f32x4;
typedef __attribute__((ext_vector_type(4))) int i32x4;
typedef __attribute__((ext_vector_type(4))) short s16x4;
typedef __attribute__((ext_vector_type(4))) unsigned short u16x4;

#define MFMA16(a,b,c) __builtin_amdgcn_mfma_f32_16x16x32_bf16((a),(b),(c),0,0,0)

__device__ __forceinline__ u16 f2bf(float x){
  unsigned int u = __float_as_uint(x);
  u += 0x7fffu + ((u >> 16) & 1u);   // RNE
  return (u16)(u >> 16);
}
__device__ __forceinline__ float bf2f(u16 x){
  return __uint_as_float(((unsigned)x) << 16);
}
// async global->LDS, 16B per lane. LDS image must be lane-linear.
__device__ __forceinline__ void gload16(const void* g, void* l){
  __builtin_amdgcn_global_load_lds((const __attribute__((address_space(1))) void*)g,
                                   (__attribute__((address_space(3))) void*)l, 16, 0, 0);
}

// ---------------------------------------------------------------------------
// prep: builds FRAGMENT-LINEAR ("P") layouts so every downstream fragment
// read is one contiguous wave transaction (kills request-issue stalls):
//   nodesP[mblk(2048)][kc(16)][q(4)][ln(16)][8]  (mblk = global row/16)
//     - serves kvq A-staging (1KB contiguous per wave) AND cmbfin phase-2 B.
//   qlbP  [mblk(512)][kc(32)][q(4)][ln(16)][8] = [q1 | last] concat in K
//   WtCP  [cb(32)][kc(16)][q(4)][ln(16)][8]
//   maskP [brt(512)][cb(64)][q(4)][ln(16)][r(4)]  (was [col][p]: 32B-stride)
//   WtKV[1024][512], WtQ2[512][1024]: row-linear (B-staging already coalesced)
// grid = 4096 x 256.
// ---------------------------------------------------------------------------
__global__ __launch_bounds__(256) void prep(
    const float* __restrict__ nodes, const float* __restrict__ q1, const float* __restrict__ lastn,
    const float* __restrict__ mask,
    const float* __restrict__ Wqf, const float* __restrict__ Wql, const float* __restrict__ Wk,
    const float* __restrict__ Wv, const float* __restrict__ Wc,
    u16* __restrict__ qlbP,
    u16* __restrict__ WtKV, u16* __restrict__ WtQ2, u16* __restrict__ WtCP,
    u16* __restrict__ nodesP, u16* __restrict__ maskP)
{
  const int tid = blockIdx.x * 256 + threadIdx.x;

  // nodesP: 2,097,152 16B-chunks, 2 per thread
  #pragma unroll
  for (int it = 0; it < 2; ++it) {
    int id = tid + it*1048576;
    int ln = id & 15, q = (id >> 4) & 3, kc = (id >> 6) & 15, cb = (id >> 10) & 63, b = id >> 16;
    const float* s = nodes + ((b*1024 + cb*16 + ln)*512 + kc*32 + q*8);
    float4 v0 = *(const float4*)s, v1 = *(const float4*)(s+4);
    u16 o[8];
    o[0]=f2bf(v0.x); o[1]=f2bf(v0.y); o[2]=f2bf(v0.z); o[3]=f2bf(v0.w);
    o[4]=f2bf(v1.x); o[5]=f2bf(v1.y); o[6]=f2bf(v1.z); o[7]=f2bf(v1.w);
    *(i32x4*)&nodesP[id*8] = *(i32x4*)&o[0];
  }

  // qlbP: 1,048,576 chunks, exactly one per thread
  {
    int ln = tid & 15, q = (tid >> 4) & 3, kc = (tid >> 6) & 31, mblk = tid >> 11;
    int m = mblk*16 + ln, k = kc*32 + q*8;
    const float* s = (k < 512) ? (q1 + m*512 + k) : (lastn + m*512 + (k - 512));
    float4 v0 = *(const float4*)s, v1 = *(const float4*)(s+4);
    u16 o[8];
    o[0]=f2bf(v0.x); o[1]=f2bf(v0.y); o[2]=f2bf(v0.z); o[3]=f2bf(v0.w);
    o[4]=f2bf(v1.x); o[5]=f2bf(v1.y); o[6]=f2bf(v1.z); o[7]=f2bf(v1.w);
    *(i32x4*)&qlbP[tid*8] = *(i32x4*)&o[0];
  }

  if (tid < 262144) {
    int n = tid >> 9, k = tid & 511;
    WtQ2[n*1024 + k]       = f2bf(Wqf[k*512 + n]);
    WtQ2[n*1024 + 512 + k] = f2bf(Wql[k*512 + n]);
  }
  if (tid < 524288) {
    int n = tid >> 9, k = tid & 511;
    WtKV[tid] = f2bf(n < 512 ? Wk[k*512 + n] : Wv[k*512 + (n-512)]);
  }
  if (tid < 32768) {   // WtCP
    int ln = tid & 15, q = (tid >> 4) & 3, kc = (tid >> 6) & 15, cb = tid >> 10;
    u16 o[8];
    #pragma unroll
    for (int e=0;e<8;e++) o[e] = f2bf(Wc[(kc*32 + q*8 + e)*512 + cb*16 + ln]);
    *(i32x4*)&WtCP[tid*8] = *(i32x4*)&o[0];
  }
  if (tid < 524288) {  // maskP: tid = brt*1024 + c
    int brt = tid >> 10, c = tid & 1023;
    const float* mp = mask + (brt*16)*1024 + c;
    u16 vals[16];
    #pragma unroll
    for (int p=0;p<16;p++) vals[p] = f2bf(mp[p*1024]);
    u16* dst = maskP + (brt*64 + (c >> 4))*256 + (c & 15)*4;
    #pragma unroll
    for (int q4=0;q4<4;q4++) {
      u16x4 v; v[0]=vals[q4*4]; v[1]=vals[q4*4+1]; v[2]=vals[q4*4+2]; v[3]=vals[q4*4+3];
      *(u16x4*)&dst[q4*64] = v;
    }
  }
}

// ---------------------------------------------------------------------------
// kvq: ONE code path, 8 waves (512 thr), 128(M)x256(N) tile, BK=32 dbuf
// (R3 schedule, measured 93.5us). A now staged from P-layout: wave w reads
// 1KB contiguous per gload16 (was coalesced before too; unchanged perf).
//   bids 0..127    : Q tiles  (A=qlbP,  B=WtQ2 [512][1024], KC=32)
//   bids 128..1151 : KV tiles (A=nodesP, B=WtKV [1024][512], KC=16)
// LDS A image per kc: [cbl(8)][q(4)][ln(16)][8]; af[i] at ((acb+i)*4+q)*128+ln*8.
// ---------------------------------------------------------------------------
__global__ __launch_bounds__(512, 2) void kvq(
    const u16* __restrict__ Akv, const u16* __restrict__ Bkv,
    const u16* __restrict__ Aq,  const u16* __restrict__ Bq,
    u16* __restrict__ Kout, u16* __restrict__ Vout, u16* __restrict__ Qout)
{
  __shared__ u16 smem[24576];   // 49152 B: 2 x (A 8KB + B 16KB)
  const int t = threadIdx.x, w = t >> 6, l = t & 63, q = l >> 4, ln = l & 15;
  const int wr = w >> 2, wc = w & 3;
  const int wm = wr * 64, wn = wc * 64;

  const bool isq = blockIdx.x < 128;
  int mb, nb, ksteps, kstr, KC;
  const u16 *Ab, *Bb;
  if (isq) {
    const int bid = blockIdx.x;
    mb = bid >> 1; nb = bid & 1;
    ksteps = 32; kstr = 1024; KC = 32; Ab = Aq; Bb = Bq;
  } else {
    const int bid = blockIdx.x - 128;
    mb = (bid >> 5)*8 + (bid & 7);        // XCD swizzle (same-A blocks share XCD)
    nb = (bid >> 3) & 3;
    ksteps = 16; kstr = 512; KC = 16; Ab = Akv; Bb = Bkv;
  }
  const int m0 = mb*128, n0 = nb*256;

  f32x4 acc[4][4];
  #pragma unroll
  for (int i=0;i<4;i++)
    #pragma unroll
    for (int j=0;j<4;j++)
      #pragma unroll
      for (int r=0;r<4;r++) acc[i][j][r] = 0.f;

  // A: P-layout. chunk = (mblk*KC + kc)*64 + (t&63); wave w = cbl -> 1KB contig
  const u16* ApL  = Ab + (((m0 >> 4) + (t >> 6))*KC*64 + (t & 63))*8;
  const u16* Baddr = Bb + (n0 + (t & 255))*kstr + (t >> 8)*8;

  #define STAGE(kc_, b_) { \
    u16* s = smem + (b_)*12288; \
    gload16(ApL + (kc_)*512,       &s[t*8]); \
    gload16(Baddr + (kc_)*32,      &s[4096 + t*8]); \
    gload16(Baddr + 16 + (kc_)*32, &s[4096 + (t+512)*8]); }

  STAGE(0, 0);
  for (int kc = 0; kc < ksteps; kc++) {
    __syncthreads();
    if (kc + 1 < ksteps) STAGE(kc+1, (kc+1)&1);
    const u16* sa = smem + (kc&1)*12288;
    const u16* sb = sa + 4096;
    const int acb = wm >> 4;
    bf16x8 af[4], bfr[4];
    #pragma unroll
    for (int i=0;i<4;i++) af[i]  = *(bf16x8*)&sa[((acb + i)*4 + q)*128 + ln*8];
    #pragma unroll
    for (int j=0;j<4;j++) bfr[j] = *(bf16x8*)&sb[(q*256 + wn + j*16 + ln)*8];
    #pragma unroll
    for (int i=0;i<4;i++)
      #pragma unroll
      for (int j=0;j<4;j++)
        acc[i][j] = MFMA16(af[i], bfr[j], acc[i][j]);
  }
  #undef STAGE

  // ---- epilogue: four 64-col passes via 64x140 buffer (17920 B) ----
  const float scale = isq ? 0.17677669529663687f : 1.0f;
  const int bb_ = mb >> 3, mloc = (mb & 7)*128;   // kv decode
  const int bbq = mb >> 1, pm0 = (mb & 1)*128;    // q  decode
  for (int h = 0; h < 4; ++h) {
    __syncthreads();
    if (wc == h) {
      #pragma unroll
      for (int i=0;i<4;i++)
        #pragma unroll
        for (int j=0;j<4;j++) {
          s16x4 o;
          #pragma unroll
          for (int r=0;r<4;r++) o[r] = (short)f2bf(acc[i][j][r]*scale);
          *(s16x4*)&smem[(j*16 + ln)*140 + wm + i*16 + q*4] = o;
        }
    }
    __syncthreads();
    #pragma unroll
    for (int hc=0; hc<2; ++hc) {
      if (isq) {
        const int head = nb*8 + h*2 + hc;
        const int m_ = t >> 2, d0 = (t & 3)*8;
        u16 v[8];
        #pragma unroll
        for (int dd=0;dd<8;dd++) v[dd] = smem[(hc*32 + d0 + dd)*140 + m_];
        *(i32x4*)&Qout[((bbq*16 + head)*256 + pm0 + m_)*32 + d0] = *(i32x4*)&v[0];
      } else if (nb < 2) {
        const int head = nb*8 + h*2 + hc;
        const int m_ = t >> 2, d0 = (t & 3)*8;
        u16 v[8];
        #pragma unroll
        for (int dd=0;dd<8;dd++) v[dd] = smem[(hc*32 + d0 + dd)*140 + m_];
        *(i32x4*)&Kout[((bb_*16 + head)*1024 + mloc + m_)*32 + d0] = *(i32x4*)&v[0];
      } else {
        const int vh = (nb-2)*8 + h*2 + hc;
        const int d = t >> 4, mo = (t & 15)*8;
        *(i32x4*)&Vout[((bb_*16 + vh)*32 + d)*1024 + mloc + mo]
            = *(i32x4*)&smem[(hc*32 + d)*140 + mo];
      }
    }
  }
}

// ---------------------------------------------------------------------------
// attn: ONE block per (b,h), 256 pomo rows, 4 waves x 64 rows. grid = 512.
// Mask fragment reads now COALESCED (512B contiguous per wave) via new maskP
// layout — was 32B-stride, 32 L2-requests/instr, ~16.7M requests total.
// XCD chunk-swizzle: bid%8 = XCD -> 4 complete batches per XCD (L2-local).
// ---------------------------------------------------------------------------
__global__ __launch_bounds__(256) void attn(const u16* __restrict__ Qg, const u16* __restrict__ Kg,
                                            const u16* __restrict__ Vtg, const u16* __restrict__ maskP,
                                            u16* __restrict__ Og)
{
  const int bid = blockIdx.x;                  // 0..511
  const int bh = (bid & 7)*64 + (bid >> 3);    // 64 consecutive bh per XCD
  const int h = bh & 15, bb = bh >> 4;
  const int t = threadIdx.x, w = t >> 6, l = t & 63, q = l >> 4, ln = l & 15;
  __shared__ u16 Qs[8192];     // [qk(4)][row(256)][8]
  __shared__ u16 Ks[4096];     // [qk(4)][m(128)][8]
  __shared__ u16 Vs[4096];     // [kg(16)][d(32)][8]
  __shared__ u16 Ps[2560];     // per wave [16][40]
  u16* Pw = &Ps[w*640];
  const int qbase = (bb*16 + h)*256*32;
  #pragma unroll
  for (int c=0;c<4;c++)
    gload16(&Qg[qbase + t*32 + c*8], &Qs[(c*256 + t)*8]);
  const int kbase = (bb*16 + h)*1024*32;
  const int vbase = (bb*16 + h)*32*1024;
  float rs[4][4];
  f32x4 oacc[4][2];
  #pragma unroll
  for (int rg=0;rg<4;rg++) {
    #pragma unroll
    for (int r=0;r<4;r++) rs[rg][r] = 0.f;
    #pragma unroll
    for (int dt=0;dt<2;dt++)
      #pragma unroll
      for (int r=0;r<4;r++) oacc[rg][dt][r] = 0.f;
  }
  __syncthreads();               // Q resident (barrier drains vmcnt)
  bf16x8 aq[4];
  #pragma unroll
  for (int rg=0;rg<4;rg++) aq[rg] = *(bf16x8*)&Qs[(q*256 + w*64 + rg*16 + ln)*8];
  const u16* mbase = maskP + (bb*16 + w*4)*16384 + q*64 + ln*4;   // + rg*16384
  u16x4 mqA[8], mqB[8];

  #define RG_BODY(rg, MQC, MQN) { \
    if ((rg) < 3) { \
      _Pragma("unroll") \
      for (int j2=0;j2<8;j2++) \
        MQN[j2] = *(const u16x4*)&mbase[((rg)+1)*16384 + (mc*8 + j2)*256]; \
    } \
    _Pragma("unroll") \
    for (int ch=0; ch<4; ch++) { \
      bf16x8 bk0 = *(bf16x8*)&Ks[(q*128 + (ch*2+0)*16 + ln)*8]; \
      bf16x8 bk1 = *(bf16x8*)&Ks[(q*128 + (ch*2+1)*16 + ln)*8]; \
      f32x4 zz = {0.f,0.f,0.f,0.f}; \
      f32x4 s0 = MFMA16(aq[rg], bk0, zz); \
      f32x4 s1 = MFMA16(aq[rg], bk1, zz); \
      _Pragma("unroll") \
      for (int r=0;r<4;r++) { \
        float e0 = __expf(s0[r] + bf2f(MQC[ch*2+0][r])); \
        float e1 = __expf(s1[r] + bf2f(MQC[ch*2+1][r])); \
        rs[rg][r] += e0 + e1; \
        Pw[(q*4+r)*40 + ln]      = f2bf(e0); \
        Pw[(q*4+r)*40 + 16 + ln] = f2bf(e1); \
      } \
      bf16x8 ap  = *(bf16x8*)&Pw[ln*40 + q*8]; \
      bf16x8 bv0 = *(bf16x8*)&Vs[((ch*4+q)*32 + ln)*8]; \
      bf16x8 bv1 = *(bf16x8*)&Vs[((ch*4+q)*32 + 16 + ln)*8]; \
      oacc[rg][0] = MFMA16(ap, bv0, oacc[rg][0]); \
      oacc[rg][1] = MFMA16(ap, bv1, oacc[rg][1]); \
    } }

  for (int mc = 0; mc < 8; mc++) {
    __syncthreads();
    gload16(&Kg[kbase + (mc*128 + (t & 127))*32 + (t >> 7)*8],       &Ks[t*8]);
    gload16(&Kg[kbase + (mc*128 + (t & 127))*32 + ((t >> 7)+2)*8],   &Ks[(t+256)*8]);
    gload16(&Vtg[vbase + (t & 31)*1024 + mc*128 + (t >> 5)*8],       &Vs[t*8]);
    gload16(&Vtg[vbase + (t & 31)*1024 + mc*128 + ((t >> 5)+8)*8],   &Vs[(t+256)*8]);
    #pragma unroll
    for (int j2=0;j2<8;j2++)
      mqA[j2] = *(const u16x4*)&mbase[(mc*8 + j2)*256];
    __syncthreads();
    RG_BODY(0, mqA, mqB)
    RG_BODY(1, mqB, mqA)
    RG_BODY(2, mqA, mqB)
    RG_BODY(3, mqB, mqA)
  }
  #undef RG_BODY

  #pragma unroll
  for (int rg=0;rg<4;rg++) {
    #pragma unroll
    for (int r=0;r<4;r++) {
      float v = rs[rg][r];
      v += __shfl_xor(v,1); v += __shfl_xor(v,2); v += __shfl_xor(v,4); v += __shfl_xor(v,8);
      rs[rg][r] = __builtin_amdgcn_rcpf(v);
    }
    const int orow = bb*256 + w*64 + rg*16 + q*4;
    #pragma unroll
    for (int dt=0;dt<2;dt++)
      #pragma unroll
      for (int r=0;r<4;r++)
        Og[(orow + r)*512 + h*32 + dt*16 + ln] = f2bf(oacc[rg][dt][r]*rs[rg][r]);
  }
}

// ---------------------------------------------------------------------------
// cmbfin: fused combine-GEMM + pointer-GEMM + tanh-softmax.
// B-operands of BOTH GEMM phases now read from fragment-linear layouts
// (WtCP, nodesP): one contiguous 1KB wave transaction per fragment (was
// 1KB-lane-stride: 64 requests/instr, ~25M requests across the dispatch).
// 1024 threads, 32 rows x 1024 cols per block, grid = 256. XCD swizzle:
// bid%8 = bb%8 -> all row-groups of batch b on one XCD (nodesP[b] 1MB in L2).
// ---------------------------------------------------------------------------
__global__ __launch_bounds__(1024) void cmbfin(const u16* __restrict__ oc, const u16* __restrict__ WtCP,
                                               const float* __restrict__ bias,
                                               const u16* __restrict__ nodesP, const u16* __restrict__ maskP,
                                               float* __restrict__ out)
{
  const int bid = blockIdx.x;
  const int bb = bid & 31, rg = bid >> 5;     // rg 0..7: 32-row group
  const int t = threadIdx.x, w = t >> 6, l = t & 63, q = l >> 4, ln = l & 15;
  __shared__ u16 As[16384];     // oc tile [koct(64)][row(32)][8]
  __shared__ u16 Ms[16384];     // mh tile, same layout (k = combine out col)
  __shared__ float rsL[16][32];
  const int abase = (bb*256 + rg*32)*512;
  #pragma unroll
  for (int c=0;c<2;c++) {
    int chunk = t + 1024*c;
    gload16(&oc[abase + (chunk & 31)*512 + (chunk >> 5)*8], &As[chunk*8]);
  }
  __syncthreads();
  // ---- phase 1: combine. wave w covers cols w*32..w*32+31 ----
  f32x4 acc1[2][2];
  #pragma unroll
  for (int i=0;i<2;i++)
    #pragma unroll
    for (int ct=0;ct<2;ct++)
      #pragma unroll
      for (int r=0;r<4;r++) acc1[i][ct][r] = 0.f;
  for (int kc=0;kc<16;kc++) {
    bf16x8 af[2];
    #pragma unroll
    for (int i=0;i<2;i++) af[i] = *(bf16x8*)&As[((kc*4 + q)*32 + i*16 + ln)*8];
    #pragma unroll
    for (int ct=0;ct<2;ct++) {
      bf16x8 bfr = *(const bf16x8*)&WtCP[(((w*2 + ct)*16 + kc)*4 + q)*128 + ln*8];
      #pragma unroll
      for (int i=0;i<2;i++) acc1[i][ct] = MFMA16(af[i], bfr, acc1[i][ct]);
    }
  }
  #pragma unroll
  for (int ct=0;ct<2;ct++) {
    int gn = w*32 + ct*16 + ln;
    float bv = bias[gn];
    #pragma unroll
    for (int i=0;i<2;i++)
      #pragma unroll
      for (int r=0;r<4;r++)
        Ms[(gn >> 3)*256 + (i*16 + q*4 + r)*8 + (gn & 7)] = f2bf(acc1[i][ct][r] + bv);
  }
  __syncthreads();
  // ---- phase 2: pointer logits + softmax. wave w covers cols w*64.. ----
  float rloc[2][4] = {{0.f,0.f,0.f,0.f},{0.f,0.f,0.f,0.f}};
  const int nbase = bb*524288;
  f32x4 acc[2][4];
  #pragma unroll
  for (int i=0;i<2;i++)
    #pragma unroll
    for (int ct=0;ct<4;ct++)
      #pragma unroll
      for (int r=0;r<4;r++) acc[i][ct][r] = 0.f;
  for (int kc=0;kc<16;kc++) {
    bf16x8 af[2];
    #pragma unroll
    for (int i=0;i<2;i++) af[i] = *(bf16x8*)&Ms[((kc*4 + q)*32 + i*16 + ln)*8];
    #pragma unroll
    for (int ct=0;ct<4;ct++) {
      bf16x8 bfr = *(const bf16x8*)&nodesP[nbase + (((w*4 + ct)*16 + kc)*4 + q)*128 + ln*8];
      #pragma unroll
      for (int i=0;i<2;i++) acc[i][ct] = MFMA16(af[i], bfr, acc[i][ct]);
    }
  }
  const float c2 = 0.08838834764831843f;   // 2/sqrt(512)
  const int prow_base = bb*256 + rg*32;
  #pragma unroll
  for (int i=0;i<2;i++) {
    #pragma unroll
    for (int ct=0;ct<4;ct++) {
      u16x4 mv = *(const u16x4*)&maskP[((bb*16 + rg*2 + i)*64 + w*4 + ct)*256 + q*64 + ln*4];
      #pragma unroll
      for (int r=0;r<4;r++) {
        float x = acc[i][ct][r] * c2;
        x = fminf(fmaxf(x, -30.f), 30.f);
        float e2 = __expf(x);
        float lg = 10.f*(e2 - 1.f)*__builtin_amdgcn_rcpf(e2 + 1.f) + bf2f(mv[r]);
        float e = __expf(lg);
        rloc[i][r] += e;
        acc[i][ct][r] = e;
      }
    }
  }
  #pragma unroll
  for (int i=0;i<2;i++)
    #pragma unroll
    for (int r=0;r<4;r++) {
      float v = rloc[i][r];
      v += __shfl_xor(v,1); v += __shfl_xor(v,2); v += __shfl_xor(v,4); v += __shfl_xor(v,8);
      rloc[i][r] = v;
    }
  if (ln == 0) {
    #pragma unroll
    for (int i=0;i<2;i++)
      #pragma unroll
      for (int r=0;r<4;r++) rsL[w][i*16 + q*4 + r] = rloc[i][r];
  }
  __syncthreads();
  float inv[2][4];
  #pragma unroll
  for (int i=0;i<2;i++)
    #pragma unroll
    for (int r=0;r<4;r++) {
      float tot = 0.f;
      #pragma unroll
      for (int ww=0;ww<16;ww++) tot += rsL[ww][i*16 + q*4 + r];
      inv[i][r] = __builtin_amdgcn_rcpf(tot);
    }
  #pragma unroll
  for (int i=0;i<2;i++)
    #pragma unroll
    for (int ct=0;ct<4;ct++) {
      int col0 = w*64 + ct*16 + ln;
      #pragma unroll
      for (int r=0;r<4;r++)
        out[(prow_base + i*16 + q*4 + r)*1024 + col0] = acc[i][ct][r]*inv[i][r];
    }
}

extern "C" void kernel_launch(void* const* d_in, const int* in_sizes, int n_in,
                              void* d_out, int out_size, void* d_ws, size_t ws_size,
                              hipStream_t stream)
{
  (void)in_sizes; (void)n_in; (void)out_size; (void)ws_size;
  const float* nodes = (const float*)d_in[0];
  const float* q1    = (const float*)d_in[1];
  const float* lastn = (const float*)d_in[2];
  const float* mask  = (const float*)d_in[3];
  const float* Wqf   = (const float*)d_in[4];
  const float* Wql   = (const float*)d_in[5];
  const float* Wk    = (const float*)d_in[6];
  const float* Wv    = (const float*)d_in[7];
  const float* Wc    = (const float*)d_in[8];
  const float* bias  = (const float*)d_in[9];
  float* out = (float*)d_out;

  char* p = (char*)d_ws;
  u16* qlbP   = (u16*)p; p += 16777216;   // [512 mblk][32 kc][4][16][8] = [q1|last]
  u16* WtKV   = (u16*)p; p += 1048576;    // [1024][512]
  u16* WtQ2   = (u16*)p; p += 1048576;    // [512][1024] = [Wqf | Wql]
  u16* WtCP   = (u16*)p; p += 524288;     // fragment-linear Wc
  u16* nodesP = (u16*)p; p += 33554432;   // [2048 mblk][16 kc][4][16][8]
  u16* maskP  = (u16*)p; p += 16777216;   // [512 brt][64 cb][4][16][4]
  u16* Kt     = (u16*)p; p += 33554432;   // K [32][16][1024][32]
  u16* Vt     = (u16*)p; p += 33554432;   // V^T [32][16][32][1024]
  u16* Qh     = (u16*)p; p += 8388608;    // Q(scaled) [32][16][256][32]
  u16* oc  = qlbP;   // dead after kvq

  prep<<<4096, 256, 0, stream>>>(nodes, q1, lastn, mask, Wqf, Wql, Wk, Wv, Wc,
                                 qlbP, WtKV, WtQ2, WtCP, nodesP, maskP);
  kvq<<<1152, 512, 0, stream>>>(nodesP, WtKV, qlbP, WtQ2, Kt, Vt, Qh);
  attn<<<512, 256, 0, stream>>>(Qh, Kt, Vt, maskP, oc);
  cmbfin<<<256, 1024, 0, stream>>>(oc, WtCP, bias, nodesP, maskP, out);
}

// Round 7
// 338.547 us; speedup vs baseline: 1.1058x; 1.0106x over previous
//
#include <hip/hip_runtime.h>
#include <math.h>

typedef unsigned short u16;
typedef __attribute__((ext_vector_type(8))) short bf16x8;
typedef __attribute__((ext_vector_type(4))) float f32x4;
typedef __attribute__((ext_vector_type(4))) int i32x4;
typedef __attribute__((ext_vector_type(4))) short s16x4;
typedef __attribute__((ext_vector_type(4))) unsigned short u16x4;

#define MFMA16(a,b,c) __builtin_amdgcn_mfma_f32_16x16x32_bf16((a),(b),(c),0,0,0)

__device__ __forceinline__ u16 f2bf(float x){
  unsigned int u = __float_as_uint(x);
  u += 0x7fffu + ((u >> 16) & 1u);   // RNE
  return (u16)(u >> 16);
}
__device__ __forceinline__ float bf2f(u16 x){
  return __uint_as_float(((unsigned)x) << 16);
}
// async global->LDS, 16B per lane. LDS image must be lane-linear.
__device__ __forceinline__ void gload16(const void* g, void* l){
  __builtin_amdgcn_global_load_lds((const __attribute__((address_space(1))) void*)g,
                                   (__attribute__((address_space(3))) void*)l, 16, 0, 0);
}

// ---------------------------------------------------------------------------
// prep: builds FRAGMENT-LINEAR ("P") layouts so every downstream fragment
// read is one contiguous wave transaction (kills request-issue stalls):
//   nodesP[mblk(2048)][kc(16)][q(4)][ln(16)][8]  (mblk = global row/16)
//     - serves kvq A-staging (1KB contiguous per wave) AND cmbfin phase-2 B.
//   qlbP  [mblk(512)][kc(32)][q(4)][ln(16)][8] = [q1 | last] concat in K
//   WtCP  [cb(32)][kc(16)][q(4)][ln(16)][8]
//   maskP [brt(512)][cb(64)][q(4)][ln(16)][r(4)]
//   WtKV[1024][512], WtQ2[512][1024]: row-linear (B-staging already coalesced)
// grid = 4096 x 256.
// ---------------------------------------------------------------------------
__global__ __launch_bounds__(256) void prep(
    const float* __restrict__ nodes, const float* __restrict__ q1, const float* __restrict__ lastn,
    const float* __restrict__ mask,
    const float* __restrict__ Wqf, const float* __restrict__ Wql, const float* __restrict__ Wk,
    const float* __restrict__ Wv, const float* __restrict__ Wc,
    u16* __restrict__ qlbP,
    u16* __restrict__ WtKV, u16* __restrict__ WtQ2, u16* __restrict__ WtCP,
    u16* __restrict__ nodesP, u16* __restrict__ maskP)
{
  const int tid = blockIdx.x * 256 + threadIdx.x;

  // nodesP: 2,097,152 16B-chunks, 2 per thread
  #pragma unroll
  for (int it = 0; it < 2; ++it) {
    int id = tid + it*1048576;
    int ln = id & 15, q = (id >> 4) & 3, kc = (id >> 6) & 15, cb = (id >> 10) & 63, b = id >> 16;
    const float* s = nodes + ((b*1024 + cb*16 + ln)*512 + kc*32 + q*8);
    float4 v0 = *(const float4*)s, v1 = *(const float4*)(s+4);
    u16 o[8];
    o[0]=f2bf(v0.x); o[1]=f2bf(v0.y); o[2]=f2bf(v0.z); o[3]=f2bf(v0.w);
    o[4]=f2bf(v1.x); o[5]=f2bf(v1.y); o[6]=f2bf(v1.z); o[7]=f2bf(v1.w);
    *(i32x4*)&nodesP[id*8] = *(i32x4*)&o[0];
  }

  // qlbP: 1,048,576 chunks, exactly one per thread
  {
    int ln = tid & 15, q = (tid >> 4) & 3, kc = (tid >> 6) & 31, mblk = tid >> 11;
    int m = mblk*16 + ln, k = kc*32 + q*8;
    const float* s = (k < 512) ? (q1 + m*512 + k) : (lastn + m*512 + (k - 512));
    float4 v0 = *(const float4*)s, v1 = *(const float4*)(s+4);
    u16 o[8];
    o[0]=f2bf(v0.x); o[1]=f2bf(v0.y); o[2]=f2bf(v0.z); o[3]=f2bf(v0.w);
    o[4]=f2bf(v1.x); o[5]=f2bf(v1.y); o[6]=f2bf(v1.z); o[7]=f2bf(v1.w);
    *(i32x4*)&qlbP[tid*8] = *(i32x4*)&o[0];
  }

  if (tid < 262144) {
    int n = tid >> 9, k = tid & 511;
    WtQ2[n*1024 + k]       = f2bf(Wqf[k*512 + n]);
    WtQ2[n*1024 + 512 + k] = f2bf(Wql[k*512 + n]);
  }
  if (tid < 524288) {
    int n = tid >> 9, k = tid & 511;
    WtKV[tid] = f2bf(n < 512 ? Wk[k*512 + n] : Wv[k*512 + (n-512)]);
  }
  if (tid < 32768) {   // WtCP
    int ln = tid & 15, q = (tid >> 4) & 3, kc = (tid >> 6) & 15, cb = tid >> 10;
    u16 o[8];
    #pragma unroll
    for (int e=0;e<8;e++) o[e] = f2bf(Wc[(kc*32 + q*8 + e)*512 + cb*16 + ln]);
    *(i32x4*)&WtCP[tid*8] = *(i32x4*)&o[0];
  }
  if (tid < 524288) {  // maskP: tid = brt*1024 + c
    int brt = tid >> 10, c = tid & 1023;
    const float* mp = mask + (brt*16)*1024 + c;
    u16 vals[16];
    #pragma unroll
    for (int p=0;p<16;p++) vals[p] = f2bf(mp[p*1024]);
    u16* dst = maskP + (brt*64 + (c >> 4))*256 + (c & 15)*4;
    #pragma unroll
    for (int q4=0;q4<4;q4++) {
      u16x4 v; v[0]=vals[q4*4]; v[1]=vals[q4*4+1]; v[2]=vals[q4*4+2]; v[3]=vals[q4*4+3];
      *(u16x4*)&dst[q4*64] = v;
    }
  }
}

// ---------------------------------------------------------------------------
// kvq: ONE code path, 8 waves (512 thr), 128(M)x256(N) tile, BK=32 dbuf
// (R6 version, measured 81us — control, unchanged).
// ---------------------------------------------------------------------------
__global__ __launch_bounds__(512, 2) void kvq(
    const u16* __restrict__ Akv, const u16* __restrict__ Bkv,
    const u16* __restrict__ Aq,  const u16* __restrict__ Bq,
    u16* __restrict__ Kout, u16* __restrict__ Vout, u16* __restrict__ Qout)
{
  __shared__ u16 smem[24576];   // 49152 B: 2 x (A 8KB + B 16KB)
  const int t = threadIdx.x, w = t >> 6, l = t & 63, q = l >> 4, ln = l & 15;
  const int wr = w >> 2, wc = w & 3;
  const int wm = wr * 64, wn = wc * 64;

  const bool isq = blockIdx.x < 128;
  int mb, nb, ksteps, kstr, KC;
  const u16 *Ab, *Bb;
  if (isq) {
    const int bid = blockIdx.x;
    mb = bid >> 1; nb = bid & 1;
    ksteps = 32; kstr = 1024; KC = 32; Ab = Aq; Bb = Bq;
  } else {
    const int bid = blockIdx.x - 128;
    mb = (bid >> 5)*8 + (bid & 7);        // XCD swizzle (same-A blocks share XCD)
    nb = (bid >> 3) & 3;
    ksteps = 16; kstr = 512; KC = 16; Ab = Akv; Bb = Bkv;
  }
  const int m0 = mb*128, n0 = nb*256;

  f32x4 acc[4][4];
  #pragma unroll
  for (int i=0;i<4;i++)
    #pragma unroll
    for (int j=0;j<4;j++)
      #pragma unroll
      for (int r=0;r<4;r++) acc[i][j][r] = 0.f;

  // A: P-layout. chunk = (mblk*KC + kc)*64 + (t&63); wave w = cbl -> 1KB contig
  const u16* ApL  = Ab + (((m0 >> 4) + (t >> 6))*KC*64 + (t & 63))*8;
  const u16* Baddr = Bb + (n0 + (t & 255))*kstr + (t >> 8)*8;

  #define STAGE(kc_, b_) { \
    u16* s = smem + (b_)*12288; \
    gload16(ApL + (kc_)*512,       &s[t*8]); \
    gload16(Baddr + (kc_)*32,      &s[4096 + t*8]); \
    gload16(Baddr + 16 + (kc_)*32, &s[4096 + (t+512)*8]); }

  STAGE(0, 0);
  for (int kc = 0; kc < ksteps; kc++) {
    __syncthreads();
    if (kc + 1 < ksteps) STAGE(kc+1, (kc+1)&1);
    const u16* sa = smem + (kc&1)*12288;
    const u16* sb = sa + 4096;
    const int acb = wm >> 4;
    bf16x8 af[4], bfr[4];
    #pragma unroll
    for (int i=0;i<4;i++) af[i]  = *(bf16x8*)&sa[((acb + i)*4 + q)*128 + ln*8];
    #pragma unroll
    for (int j=0;j<4;j++) bfr[j] = *(bf16x8*)&sb[(q*256 + wn + j*16 + ln)*8];
    #pragma unroll
    for (int i=0;i<4;i++)
      #pragma unroll
      for (int j=0;j<4;j++)
        acc[i][j] = MFMA16(af[i], bfr[j], acc[i][j]);
  }
  #undef STAGE

  // ---- epilogue: four 64-col passes via 64x140 buffer (17920 B) ----
  const float scale = isq ? 0.17677669529663687f : 1.0f;
  const int bb_ = mb >> 3, mloc = (mb & 7)*128;   // kv decode
  const int bbq = mb >> 1, pm0 = (mb & 1)*128;    // q  decode
  for (int h = 0; h < 4; ++h) {
    __syncthreads();
    if (wc == h) {
      #pragma unroll
      for (int i=0;i<4;i++)
        #pragma unroll
        for (int j=0;j<4;j++) {
          s16x4 o;
          #pragma unroll
          for (int r=0;r<4;r++) o[r] = (short)f2bf(acc[i][j][r]*scale);
          *(s16x4*)&smem[(j*16 + ln)*140 + wm + i*16 + q*4] = o;
        }
    }
    __syncthreads();
    #pragma unroll
    for (int hc=0; hc<2; ++hc) {
      if (isq) {
        const int head = nb*8 + h*2 + hc;
        const int m_ = t >> 2, d0 = (t & 3)*8;
        u16 v[8];
        #pragma unroll
        for (int dd=0;dd<8;dd++) v[dd] = smem[(hc*32 + d0 + dd)*140 + m_];
        *(i32x4*)&Qout[((bbq*16 + head)*256 + pm0 + m_)*32 + d0] = *(i32x4*)&v[0];
      } else if (nb < 2) {
        const int head = nb*8 + h*2 + hc;
        const int m_ = t >> 2, d0 = (t & 3)*8;
        u16 v[8];
        #pragma unroll
        for (int dd=0;dd<8;dd++) v[dd] = smem[(hc*32 + d0 + dd)*140 + m_];
        *(i32x4*)&Kout[((bb_*16 + head)*1024 + mloc + m_)*32 + d0] = *(i32x4*)&v[0];
      } else {
        const int vh = (nb-2)*8 + h*2 + hc;
        const int d = t >> 4, mo = (t & 15)*8;
        *(i32x4*)&Vout[((bb_*16 + vh)*32 + d)*1024 + mloc + mo]
            = *(i32x4*)&smem[(hc*32 + d)*140 + mo];
      }
    }
  }
}

// ---------------------------------------------------------------------------
// attn v3: K/V DOUBLE-BUFFERED with the kvq-R3 schedule — one barrier per
// mc, next chunk's 4 gload16 issued right after the publish barrier so the
// 4 RG-bodies (~2000+ cyc MFMA+exp) cover the load latency. v2 issued loads
// between two back-to-back barriers: ~700 cyc exposed drain x 8 mc.
// Also: P scratch double-buffered by ch parity (breaks write->read->overwrite
// serialization); rg0 mask fragment prefetched during rg3 of previous mc
// (full-circle A/B register alternation, all indices static; the mc=7 tail
// prefetch is in-bounds-but-unused).
// One block per (b,h), 4 waves x 64 rows. grid = 512 (2 blocks/CU).
// LDS 58KB -> still 2 blocks/CU. XCD chunk-swizzle: bid%8 = XCD.
// ---------------------------------------------------------------------------
__global__ __launch_bounds__(256) void attn(const u16* __restrict__ Qg, const u16* __restrict__ Kg,
                                            const u16* __restrict__ Vtg, const u16* __restrict__ maskP,
                                            u16* __restrict__ Og)
{
  const int bid = blockIdx.x;                  // 0..511
  const int bh = (bid & 7)*64 + (bid >> 3);    // 64 consecutive bh per XCD
  const int h = bh & 15, bb = bh >> 4;
  const int t = threadIdx.x, w = t >> 6, l = t & 63, q = l >> 4, ln = l & 15;
  __shared__ u16 Qs[8192];       // [qk(4)][row(256)][8]
  __shared__ u16 Ks[2][4096];    // dbuf [qk(4)][m(128)][8]
  __shared__ u16 Vs[2][4096];    // dbuf [kg(16)][d(32)][8]
  __shared__ u16 Ps[5120];       // 2 x per-wave [16][40]
  u16* PwA = &Ps[w*640];
  u16* PwB = &Ps[2560 + w*640];
  const int qbase = (bb*16 + h)*256*32;
  #pragma unroll
  for (int c=0;c<4;c++)
    gload16(&Qg[qbase + t*32 + c*8], &Qs[(c*256 + t)*8]);
  const int kbase = (bb*16 + h)*1024*32;
  const int vbase = (bb*16 + h)*32*1024;

  #define STAGE_KV(mc_, b_) { \
    gload16(&Kg[kbase + ((mc_)*128 + (t & 127))*32 + (t >> 7)*8],     &Ks[b_][t*8]); \
    gload16(&Kg[kbase + ((mc_)*128 + (t & 127))*32 + ((t >> 7)+2)*8], &Ks[b_][(t+256)*8]); \
    gload16(&Vtg[vbase + (t & 31)*1024 + (mc_)*128 + (t >> 5)*8],     &Vs[b_][t*8]); \
    gload16(&Vtg[vbase + (t & 31)*1024 + (mc_)*128 + ((t >> 5)+8)*8], &Vs[b_][(t+256)*8]); }

  STAGE_KV(0, 0)

  float rs[4][4];
  f32x4 oacc[4][2];
  #pragma unroll
  for (int rg=0;rg<4;rg++) {
    #pragma unroll
    for (int r=0;r<4;r++) rs[rg][r] = 0.f;
    #pragma unroll
    for (int dt=0;dt<2;dt++)
      #pragma unroll
      for (int r=0;r<4;r++) oacc[rg][dt][r] = 0.f;
  }
  __syncthreads();               // Q + K/V chunk 0 resident
  bf16x8 aq[4];
  #pragma unroll
  for (int rg=0;rg<4;rg++) aq[rg] = *(bf16x8*)&Qs[(q*256 + w*64 + rg*16 + ln)*8];
  const u16* mbase = maskP + (bb*16 + w*4)*16384 + q*64 + ln*4;   // + rg*16384
  u16x4 mqA[8], mqB[8];
  #pragma unroll
  for (int j2=0;j2<8;j2++) mqA[j2] = *(const u16x4*)&mbase[j2*256];   // mc0, rg0

  #define RG_BODY(rg, MQC, MQN, PRRG, PRMC) { \
    _Pragma("unroll") \
    for (int j2=0;j2<8;j2++) \
      MQN[j2] = *(const u16x4*)&mbase[(PRRG)*16384 + ((PRMC)*8 + j2)*256]; \
    _Pragma("unroll") \
    for (int ch=0; ch<4; ch++) { \
      u16* Pc = (ch & 1) ? PwB : PwA; \
      bf16x8 bk0 = *(bf16x8*)&Kc[(q*128 + (ch*2+0)*16 + ln)*8]; \
      bf16x8 bk1 = *(bf16x8*)&Kc[(q*128 + (ch*2+1)*16 + ln)*8]; \
      f32x4 zz = {0.f,0.f,0.f,0.f}; \
      f32x4 s0 = MFMA16(aq[rg], bk0, zz); \
      f32x4 s1 = MFMA16(aq[rg], bk1, zz); \
      _Pragma("unroll") \
      for (int r=0;r<4;r++) { \
        float e0 = __expf(s0[r] + bf2f(MQC[ch*2+0][r])); \
        float e1 = __expf(s1[r] + bf2f(MQC[ch*2+1][r])); \
        rs[rg][r] += e0 + e1; \
        Pc[(q*4+r)*40 + ln]      = f2bf(e0); \
        Pc[(q*4+r)*40 + 16 + ln] = f2bf(e1); \
      } \
      bf16x8 ap  = *(bf16x8*)&Pc[ln*40 + q*8]; \
      bf16x8 bv0 = *(bf16x8*)&Vc[((ch*4+q)*32 + ln)*8]; \
      bf16x8 bv1 = *(bf16x8*)&Vc[((ch*4+q)*32 + 16 + ln)*8]; \
      oacc[rg][0] = MFMA16(ap, bv0, oacc[rg][0]); \
      oacc[rg][1] = MFMA16(ap, bv1, oacc[rg][1]); \
    } }

  for (int mc = 0; mc < 8; mc++) {
    if (mc) __syncthreads();           // K/V[mc&1] ready; buf (mc+1)&1 free
    if (mc < 7) STAGE_KV(mc+1, (mc+1)&1)
    const u16* Kc = Ks[mc&1];
    const u16* Vc = Vs[mc&1];
    RG_BODY(0, mqA, mqB, 1, mc)
    RG_BODY(1, mqB, mqA, 2, mc)
    RG_BODY(2, mqA, mqB, 3, mc)
    RG_BODY(3, mqB, mqA, 0, (mc+1))
  }
  #undef RG_BODY
  #undef STAGE_KV

  #pragma unroll
  for (int rg=0;rg<4;rg++) {
    #pragma unroll
    for (int r=0;r<4;r++) {
      float v = rs[rg][r];
      v += __shfl_xor(v,1); v += __shfl_xor(v,2); v += __shfl_xor(v,4); v += __shfl_xor(v,8);
      rs[rg][r] = __builtin_amdgcn_rcpf(v);
    }
    const int orow = bb*256 + w*64 + rg*16 + q*4;
    #pragma unroll
    for (int dt=0;dt<2;dt++)
      #pragma unroll
      for (int r=0;r<4;r++)
        Og[(orow + r)*512 + h*32 + dt*16 + ln] = f2bf(oacc[rg][dt][r]*rs[rg][r]);
  }
}

// ---------------------------------------------------------------------------
// cmbfin: fused combine-GEMM + pointer-GEMM + tanh-softmax.
// B-operands fragment-linear (WtCP, nodesP). kc loops partially unrolled so
// the compiler hoists B-fragment loads across iterations (latency cover).
// 1024 threads, 32 rows x 1024 cols per block, grid = 256.
// ---------------------------------------------------------------------------
__global__ __launch_bounds__(1024) void cmbfin(const u16* __restrict__ oc, const u16* __restrict__ WtCP,
                                               const float* __restrict__ bias,
                                               const u16* __restrict__ nodesP, const u16* __restrict__ maskP,
                                               float* __restrict__ out)
{
  const int bid = blockIdx.x;
  const int bb = bid & 31, rg = bid >> 5;     // rg 0..7: 32-row group
  const int t = threadIdx.x, w = t >> 6, l = t & 63, q = l >> 4, ln = l & 15;
  __shared__ u16 As[16384];     // oc tile [koct(64)][row(32)][8]
  __shared__ u16 Ms[16384];     // mh tile, same layout (k = combine out col)
  __shared__ float rsL[16][32];
  const int abase = (bb*256 + rg*32)*512;
  #pragma unroll
  for (int c=0;c<2;c++) {
    int chunk = t + 1024*c;
    gload16(&oc[abase + (chunk & 31)*512 + (chunk >> 5)*8], &As[chunk*8]);
  }
  __syncthreads();
  // ---- phase 1: combine. wave w covers cols w*32..w*32+31 ----
  f32x4 acc1[2][2];
  #pragma unroll
  for (int i=0;i<2;i++)
    #pragma unroll
    for (int ct=0;ct<2;ct++)
      #pragma unroll
      for (int r=0;r<4;r++) acc1[i][ct][r] = 0.f;
  #pragma unroll 4
  for (int kc=0;kc<16;kc++) {
    bf16x8 af[2];
    #pragma unroll
    for (int i=0;i<2;i++) af[i] = *(bf16x8*)&As[((kc*4 + q)*32 + i*16 + ln)*8];
    #pragma unroll
    for (int ct=0;ct<2;ct++) {
      bf16x8 bfr = *(const bf16x8*)&WtCP[(((w*2 + ct)*16 + kc)*4 + q)*128 + ln*8];
      #pragma unroll
      for (int i=0;i<2;i++) acc1[i][ct] = MFMA16(af[i], bfr, acc1[i][ct]);
    }
  }
  #pragma unroll
  for (int ct=0;ct<2;ct++) {
    int gn = w*32 + ct*16 + ln;
    float bv = bias[gn];
    #pragma unroll
    for (int i=0;i<2;i++)
      #pragma unroll
      for (int r=0;r<4;r++)
        Ms[(gn >> 3)*256 + (i*16 + q*4 + r)*8 + (gn & 7)] = f2bf(acc1[i][ct][r] + bv);
  }
  __syncthreads();
  // ---- phase 2: pointer logits + softmax. wave w covers cols w*64.. ----
  float rloc[2][4] = {{0.f,0.f,0.f,0.f},{0.f,0.f,0.f,0.f}};
  const int nbase = bb*524288;
  f32x4 acc[2][4];
  #pragma unroll
  for (int i=0;i<2;i++)
    #pragma unroll
    for (int ct=0;ct<4;ct++)
      #pragma unroll
      for (int r=0;r<4;r++) acc[i][ct][r] = 0.f;
  #pragma unroll 2
  for (int kc=0;kc<16;kc++) {
    bf16x8 af[2];
    #pragma unroll
    for (int i=0;i<2;i++) af[i] = *(bf16x8*)&Ms[((kc*4 + q)*32 + i*16 + ln)*8];
    #pragma unroll
    for (int ct=0;ct<4;ct++) {
      bf16x8 bfr = *(const bf16x8*)&nodesP[nbase + (((w*4 + ct)*16 + kc)*4 + q)*128 + ln*8];
      #pragma unroll
      for (int i=0;i<2;i++) acc[i][ct] = MFMA16(af[i], bfr, acc[i][ct]);
    }
  }
  const float c2 = 0.08838834764831843f;   // 2/sqrt(512)
  const int prow_base = bb*256 + rg*32;
  #pragma unroll
  for (int i=0;i<2;i++) {
    #pragma unroll
    for (int ct=0;ct<4;ct++) {
      u16x4 mv = *(const u16x4*)&maskP[((bb*16 + rg*2 + i)*64 + w*4 + ct)*256 + q*64 + ln*4];
      #pragma unroll
      for (int r=0;r<4;r++) {
        float x = acc[i][ct][r] * c2;
        x = fminf(fmaxf(x, -30.f), 30.f);
        float e2 = __expf(x);
        float lg = 10.f*(e2 - 1.f)*__builtin_amdgcn_rcpf(e2 + 1.f) + bf2f(mv[r]);
        float e = __expf(lg);
        rloc[i][r] += e;
        acc[i][ct][r] = e;
      }
    }
  }
  #pragma unroll
  for (int i=0;i<2;i++)
    #pragma unroll
    for (int r=0;r<4;r++) {
      float v = rloc[i][r];
      v += __shfl_xor(v,1); v += __shfl_xor(v,2); v += __shfl_xor(v,4); v += __shfl_xor(v,8);
      rloc[i][r] = v;
    }
  if (ln == 0) {
    #pragma unroll
    for (int i=0;i<2;i++)
      #pragma unroll
      for (int r=0;r<4;r++) rsL[w][i*16 + q*4 + r] = rloc[i][r];
  }
  __syncthreads();
  float inv[2][4];
  #pragma unroll
  for (int i=0;i<2;i++)
    #pragma unroll
    for (int r=0;r<4;r++) {
      float tot = 0.f;
      #pragma unroll
      for (int ww=0;ww<16;ww++) tot += rsL[ww][i*16 + q*4 + r];
      inv[i][r] = __builtin_amdgcn_rcpf(tot);
    }
  #pragma unroll
  for (int i=0;i<2;i++)
    #pragma unroll
    for (int ct=0;ct<4;ct++) {
      int col0 = w*64 + ct*16 + ln;
      #pragma unroll
      for (int r=0;r<4;r++)
        out[(prow_base + i*16 + q*4 + r)*1024 + col0] = acc[i][ct][r]*inv[i][r];
    }
}

extern "C" void kernel_launch(void* const* d_in, const int* in_sizes, int n_in,
                              void* d_out, int out_size, void* d_ws, size_t ws_size,
                              hipStream_t stream)
{
  (void)in_sizes; (void)n_in; (void)out_size; (void)ws_size;
  const float* nodes = (const float*)d_in[0];
  const float* q1    = (const float*)d_in[1];
  const float* lastn = (const float*)d_in[2];
  const float* mask  = (const float*)d_in[3];
  const float* Wqf   = (const float*)d_in[4];
  const float* Wql   = (const float*)d_in[5];
  const float* Wk    = (const float*)d_in[6];
  const float* Wv    = (const float*)d_in[7];
  const float* Wc    = (const float*)d_in[8];
  const float* bias  = (const float*)d_in[9];
  float* out = (float*)d_out;

  char* p = (char*)d_ws;
  u16* qlbP   = (u16*)p; p += 16777216;   // [512 mblk][32 kc][4][16][8] = [q1|last]
  u16* WtKV   = (u16*)p; p += 1048576;    // [1024][512]
  u16* WtQ2   = (u16*)p; p += 1048576;    // [512][1024] = [Wqf | Wql]
  u16* WtCP   = (u16*)p; p += 524288;     // fragment-linear Wc
  u16* nodesP = (u16*)p; p += 33554432;   // [2048 mblk][16 kc][4][16][8]
  u16* maskP  = (u16*)p; p += 16777216;   // [512 brt][64 cb][4][16][4]
  u16* Kt     = (u16*)p; p += 33554432;   // K [32][16][1024][32]
  u16* Vt     = (u16*)p; p += 33554432;   // V^T [32][16][32][1024]
  u16* Qh     = (u16*)p; p += 8388608;    // Q(scaled) [32][16][256][32]
  u16* oc  = qlbP;   // dead after kvq

  prep<<<4096, 256, 0, stream>>>(nodes, q1, lastn, mask, Wqf, Wql, Wk, Wv, Wc,
                                 qlbP, WtKV, WtQ2, WtCP, nodesP, maskP);
  kvq<<<1152, 512, 0, stream>>>(nodesP, WtKV, qlbP, WtQ2, Kt, Vt, Qh);
  attn<<<512, 256, 0, stream>>>(Qh, Kt, Vt, maskP, oc);
  cmbfin<<<256, 1024, 0, stream>>>(oc, WtCP, bias, nodesP, maskP, out);
}